// Round 9
// baseline (143.382 us; speedup 1.0000x reference)
//
#include <hip/hip_runtime.h>
#include <hip/hip_bf16.h>

#define N_NODES 100000
#define DN      256
#define DE      128
#define DOUT    256
#define M1      32768
#define BSZ     8192
#define E1      327680
#define E2      81920
#define DIN     640
#define DAGG    384
#define WELEMS  (DOUT * DIN)

#define CDIV(a,b) (((a)+(b)-1)/(b))

// zero region: cnt1[M1] cnt2[BSZ] mark[M1] nn[64] zrow[256] — contiguous ints at ws base
#define ZERO_INTS (M1 + BSZ + M1 + 64 + 256)
#define S1_ZB 73            // CDIV(ZERO_INTS, 1024)
#define S1_CB 80            // 2*WELEMS / 4 / 1024
#define S2_MB 8             // BSZ / 1024
#define S2_CB 400           // (E1+E2) / 1024
#define S3_KB 32            // M1 / 1024
#define S4_EB 400           // edge blocks in setup4
#define S4_DB 16            // desc blocks: 8 for wdesc1, 8 for wdesc2

typedef __attribute__((ext_vector_type(8))) short bf16x8;
typedef __attribute__((ext_vector_type(4))) float f32x4;
typedef __attribute__((ext_vector_type(2))) float f32x2;
typedef __attribute__((ext_vector_type(4))) unsigned short u16x4;
typedef __attribute__((ext_vector_type(2))) unsigned short u16x2;

__device__ __forceinline__ unsigned short f32_bf16(float f) {
  unsigned u = __float_as_uint(f);
  unsigned r = (u + 0x7FFF + ((u >> 16) & 1)) >> 16;
  return (unsigned short)r;
}

// ---- setup1: zero bookkeeping region + convert W1/W2 to bf16 --------------

__global__ __launch_bounds__(1024) void setup1_kernel(int* __restrict__ zbase,
                                                      const float* __restrict__ W1,
                                                      const float* __restrict__ W2,
                                                      unsigned short* __restrict__ Wb1,
                                                      unsigned short* __restrict__ Wb2) {
  int b = blockIdx.x, t = threadIdx.x;
  if (b < S1_ZB) {
    int i = b * 1024 + t;
    if (i < ZERO_INTS) zbase[i] = 0;
  } else {
    int i = ((b - S1_ZB) * 1024 + t) * 4;
    const float* s; unsigned short* d; int o;
    if (i < WELEMS) { s = W1; d = Wb1; o = i; }
    else { s = W2; d = Wb2; o = i - WELEMS; }
    f32x4 v = *reinterpret_cast<const f32x4*>(s + o);
    u16x4 r;
    r[0] = f32_bf16(v[0]); r[1] = f32_bf16(v[1]);
    r[2] = f32_bf16(v[2]); r[3] = f32_bf16(v[3]);
    *reinterpret_cast<u16x4*>(d + o) = r;
  }
}

// ---- setup2: mark live layer-1 segments + count ALL edges per segment -----

__global__ __launch_bounds__(1024) void setup2_kernel(const int* __restrict__ self2,
                                                      int* __restrict__ mark,
                                                      const int* __restrict__ seg1,
                                                      int* __restrict__ cnt1,
                                                      const int* __restrict__ seg2,
                                                      int* __restrict__ cnt2) {
  int b = blockIdx.x, t = threadIdx.x;
  if (b < S2_MB) {
    mark[self2[b * 1024 + t]] = 1;
  } else {
    int e = (b - S2_MB) * 1024 + t;
    if (e < E1) atomicAdd(&cnt1[seg1[e]], 1);
    else atomicAdd(&cnt2[seg2[e - E1]], 1);
  }
}

// ---- setup3: compact marked segments + exclusive scans --------------------

__device__ __forceinline__ void scan1024(const int* __restrict__ cnt,
                                         int* __restrict__ off,
                                         int* __restrict__ cur,
                                         int n, int* wsum) {
  int t = threadIdx.x;
  int per = n >> 10;
  int base = t * per;
  int s = 0;
  for (int j = 0; j < per; ++j) s += cnt[base + j];
  int lane = t & 63, wid = t >> 6;
  int v = s;
  for (int d = 1; d < 64; d <<= 1) {
    int u = __shfl_up(v, d);
    if (lane >= d) v += u;
  }
  if (lane == 63) wsum[wid] = v;
  __syncthreads();
  if (t == 0) {
    int run = 0;
    for (int wi = 0; wi < 16; ++wi) { int x = wsum[wi]; wsum[wi] = run; run += x; }
    off[n] = run;
  }
  __syncthreads();
  int excl = wsum[wid] + (v - s);
  int run = excl;
  for (int j = 0; j < per; ++j) {
    off[base + j] = run;
    cur[base + j] = run;
    run += cnt[base + j];
  }
}

__global__ __launch_bounds__(1024) void setup3_kernel(const int* __restrict__ mark,
                                                      const int* __restrict__ self1,
                                                      int* __restrict__ remap,
                                                      int* __restrict__ needed,
                                                      int* __restrict__ selfrow1,
                                                      int* __restrict__ nn,
                                                      const int* __restrict__ cnt1,
                                                      int* __restrict__ off1,
                                                      int* __restrict__ cur1,
                                                      const int* __restrict__ cnt2,
                                                      int* __restrict__ off2,
                                                      int* __restrict__ cur2) {
  __shared__ int wsum[16];
  int b = blockIdx.x;
  if (b < S3_KB) {
    int m = b * 1024 + threadIdx.x;
    if (mark[m]) {
      int p = atomicAdd(nn, 1);
      remap[m] = p;
      needed[p] = m;
      selfrow1[p] = self1[m];
    }
  } else if (b == S3_KB) {
    scan1024(cnt1, off1, cur1, M1, wsum);
  } else {
    scan1024(cnt2, off2, cur2, BSZ, wsum);
  }
}

// ---- setup4: scatter (mark-filtered layer-1) + build per-slot descriptors -

__global__ __launch_bounds__(1024) void setup4_kernel(const int* __restrict__ seg1,
                                                      const int* __restrict__ mark,
                                                      int* __restrict__ cur1,
                                                      int* __restrict__ order1,
                                                      int* __restrict__ fidx1,
                                                      const int* __restrict__ from1,
                                                      const int* __restrict__ seg2,
                                                      int* __restrict__ cur2,
                                                      int* __restrict__ order2,
                                                      int* __restrict__ fidx2,
                                                      const int* __restrict__ from2,
                                                      const int* __restrict__ nn,
                                                      const int* __restrict__ needed,
                                                      const int* __restrict__ off1,
                                                      const int* __restrict__ off2,
                                                      int2* __restrict__ wdesc) {
  int b = blockIdx.x, t = threadIdx.x;
  if (b < S4_EB) {
    int e = b * 1024 + t;
    if (e < E1) {
      int s = seg1[e];
      if (mark[s]) {
        int p = atomicAdd(&cur1[s], 1);
        order1[p] = e;
        fidx1[p] = from1[e];
      }
    } else {
      int e2 = e - E1;
      int p = atomicAdd(&cur2[seg2[e2]], 1);
      order2[p] = e2;
      fidx2[p] = from2[e2];
    }
  } else if (b < S4_EB + 8) {
    int p = (b - S4_EB) * 1024 + t;          // layer-1 slot
    int2 d = make_int2(0, 0);
    if (p < *nn) { int m = needed[p]; d = make_int2(off1[m], off1[m + 1]); }
    wdesc[p] = d;
  } else {
    int r = (b - S4_EB - 8) * 1024 + t;      // layer-2 slot
    wdesc[8192 + r] = make_int2(off2[r], off2[r + 1]);
  }
}

// ---- aggregation: 4 segments per wave (unchanged from R8) -----------------

__global__ __launch_bounds__(256) void agg_kernel(const int2* __restrict__ wdesc,
                                                  const int* __restrict__ order1,
                                                  const int* __restrict__ fidx1,
                                                  const float* __restrict__ ef1,
                                                  unsigned short* __restrict__ agg1,
                                                  const int* __restrict__ order2,
                                                  const int* __restrict__ fidx2,
                                                  const float* __restrict__ ef2,
                                                  unsigned short* __restrict__ agg2,
                                                  const float* __restrict__ nf,
                                                  const float* __restrict__ zrow) {
  int wv = (blockIdx.x * 256 + threadIdx.x) >> 6;   // 0..4095
  int l = threadIdx.x & 63;
  int s0 = wv * 4;                                   // slot base (layer-aligned)
  bool lay1 = s0 < 8192;
  const int* order = lay1 ? order1 : order2;
  const int* fidx  = lay1 ? fidx1  : fidx2;
  const float* ef  = lay1 ? ef1 : ef2;
  unsigned short* aggout = lay1 ? agg1 : agg2;
  int rbase = lay1 ? s0 : s0 - 8192;

  int e0v[4], e1v[4];
#pragma unroll
  for (int s = 0; s < 4; ++s) {
    int2 d = wdesc[s0 + s];
    e0v[s] = d.x; e1v[s] = d.y;
  }

  f32x4 accn[4];
  f32x2 accf[4];
  int eidp[4], fidp[4];
#pragma unroll
  for (int s = 0; s < 4; ++s) {
    accn[s] = (f32x4)0.f;
    accf[s] = (f32x2)0.f;
    int nc = min(64, e1v[s] - e0v[s]);
    eidp[s] = 0; fidp[s] = 0;
    if (l < nc) {
      eidp[s] = order[e0v[s] + l];
      fidp[s] = fidx[e0v[s] + l];
    }
  }

  const float* zra = zrow + l * 4;   // 16B of zeros per lane
  const float* zrb = zrow + l * 2;

#pragma unroll
  for (int s = 0; s < 4; ++s) {
    int E0 = e0v[s], E1c = e1v[s];
    for (int c0 = E0; c0 < E1c; c0 += 64) {
      int nc = min(64, E1c - c0);
      int eid, fid;
      if (c0 == E0) { eid = eidp[s]; fid = fidp[s]; }
      else {
        eid = 0; fid = 0;
        if (l < nc) { eid = order[c0 + l]; fid = fidx[c0 + l]; }
      }
      for (int j = 0; j < nc; j += 8) {
        f32x4 a[8]; f32x2 b[8];
#pragma unroll
        for (int q = 0; q < 8; ++q) {
          int jj = j + q;
          int fq = __shfl(fid, jj & 63);
          int gq = __shfl(eid, jj & 63);
          bool ok = jj < nc;
          const float* pa = ok ? (nf + (size_t)fq * 256 + l * 4) : zra;
          const float* pb = ok ? (ef + (size_t)gq * 128 + l * 2) : zrb;
          a[q] = *reinterpret_cast<const f32x4*>(pa);
          b[q] = *reinterpret_cast<const f32x2*>(pb);
        }
        accn[s] += ((a[0] + a[1]) + (a[2] + a[3])) + ((a[4] + a[5]) + (a[6] + a[7]));
        accf[s] += ((b[0] + b[1]) + (b[2] + b[3])) + ((b[4] + b[5]) + (b[6] + b[7]));
      }
    }
  }

#pragma unroll
  for (int s = 0; s < 4; ++s) {
    unsigned short* orow = aggout + (size_t)(rbase + s) * DAGG;
    u16x4 on;
    on[0] = f32_bf16(accn[s][0]); on[1] = f32_bf16(accn[s][1]);
    on[2] = f32_bf16(accn[s][2]); on[3] = f32_bf16(accn[s][3]);
    *reinterpret_cast<u16x4*>(orow + l * 4) = on;
    u16x2 oe;
    oe[0] = f32_bf16(accf[s][0]); oe[1] = f32_bf16(accf[s][1]);
    *reinterpret_cast<u16x2*>(orow + 256 + l * 2) = oe;
  }
}

// ---- MFMA GEMM (R3 known-good shape): BM=128, BN=64, BK=32 ----------------
// MODE 0 (layer1): table = nf (f32), row = i1[r];        out = bf16 h1
// MODE 1 (layer2): table = h1 (bf16), row = i2[i1[r]];   out = f32 final
// 4 waves in 2x2; per wave 4x2 frags of 16x16x32.

template<int MODE>
__global__ __launch_bounds__(256) void gemm_mfma_kernel(const float* __restrict__ tabf,
                                                        const unsigned short* __restrict__ tabb,
                                                        const int* __restrict__ i1,
                                                        const int* __restrict__ i2,
                                                        const unsigned short* __restrict__ agg,
                                                        const unsigned short* __restrict__ Wb,
                                                        float* __restrict__ outf,
                                                        unsigned short* __restrict__ outb,
                                                        const int* __restrict__ nn_dev,
                                                        int nrows_c) {
  const int nrows = nn_dev ? *nn_dev : nrows_c;
  const int row0 = blockIdx.x * 128;
  if (row0 >= nrows) return;
  const int col0 = blockIdx.y * 64;

  __shared__ unsigned short As[128][40];  // 80B row stride: 16B-aligned, low conflict
  __shared__ unsigned short Bs[64][40];

  const int t = threadIdx.x;
  const int lane = t & 63, wid = t >> 6;
  const int wm = wid >> 1, wn = wid & 1;

  // staging geometry: thread t stages A rows (t>>2) and (t>>2)+64, k-oct (t&3)*8
  const int arow = t >> 2;
  const int akg = (t & 3) * 8;
  const int grow0 = row0 + arow;
  const int grow1 = row0 + arow + 64;
  int ga0 = -1, ga1 = -1;
  if (grow0 < nrows) { int x = i1[grow0]; ga0 = (MODE == 1) ? i2[x] : x; }
  if (grow1 < nrows) { int x = i1[grow1]; ga1 = (MODE == 1) ? i2[x] : x; }

  const int bn_ = t >> 2;  // B stage: col (t>>2), same k-oct
  const unsigned short* wrow = Wb + (size_t)(col0 + bn_) * DIN;

  f32x4 acc[4][2];
#pragma unroll
  for (int m = 0; m < 4; ++m)
#pragma unroll
    for (int n = 0; n < 2; ++n) acc[m][n] = (f32x4)0.f;

  auto loadA = [&](int ga, int grow, int k) -> bf16x8 {
    bf16x8 v = (bf16x8)(short)0;
    if (ga < 0) return v;
    if (k < 256) {
      if (MODE == 0) {
        const float* s = tabf + (size_t)ga * 256 + k;
        f32x4 x0 = *reinterpret_cast<const f32x4*>(s);
        f32x4 x1 = *reinterpret_cast<const f32x4*>(s + 4);
#pragma unroll
        for (int j = 0; j < 4; ++j) {
          v[j] = (short)f32_bf16(x0[j]);
          v[4 + j] = (short)f32_bf16(x1[j]);
        }
      } else {
        v = *reinterpret_cast<const bf16x8*>(tabb + (size_t)ga * 256 + k);
      }
    } else {
      v = *reinterpret_cast<const bf16x8*>(agg + (size_t)grow * DAGG + (k - 256));
    }
    return v;
  };

  for (int k0 = 0; k0 < DIN; k0 += 32) {
    *reinterpret_cast<bf16x8*>(&As[arow][akg]) = loadA(ga0, grow0, k0 + akg);
    *reinterpret_cast<bf16x8*>(&As[arow + 64][akg]) = loadA(ga1, grow1, k0 + akg);
    *reinterpret_cast<bf16x8*>(&Bs[bn_][akg]) =
        *reinterpret_cast<const bf16x8*>(wrow + k0 + akg);
    __syncthreads();

    bf16x8 af[4], bg[2];
#pragma unroll
    for (int m = 0; m < 4; ++m)
      af[m] = *reinterpret_cast<const bf16x8*>(&As[wm * 64 + m * 16 + (lane & 15)][(lane >> 4) * 8]);
#pragma unroll
    for (int n = 0; n < 2; ++n)
      bg[n] = *reinterpret_cast<const bf16x8*>(&Bs[wn * 32 + n * 16 + (lane & 15)][(lane >> 4) * 8]);
#pragma unroll
    for (int m = 0; m < 4; ++m)
#pragma unroll
      for (int n = 0; n < 2; ++n)
        acc[m][n] = __builtin_amdgcn_mfma_f32_16x16x32_bf16(af[m], bg[n], acc[m][n], 0, 0, 0);
    __syncthreads();
  }

  const int rbase = row0 + wm * 64;
  const int cbase = col0 + wn * 32;
#pragma unroll
  for (int m = 0; m < 4; ++m)
#pragma unroll
    for (int n = 0; n < 2; ++n)
#pragma unroll
      for (int g = 0; g < 4; ++g) {
        int r = rbase + m * 16 + (lane >> 4) * 4 + g;
        if (r < nrows) {
          int c = cbase + n * 16 + (lane & 15);
          float x = fmaxf(acc[m][n][g], 0.f);
          if (MODE == 0) outb[(size_t)r * DOUT + c] = f32_bf16(x);
          else outf[(size_t)r * DOUT + c] = x;
        }
      }
}

// ---- launcher ------------------------------------------------------------

extern "C" void kernel_launch(void* const* d_in, const int* in_sizes, int n_in,
                              void* d_out, int out_size, void* d_ws, size_t ws_size,
                              hipStream_t stream) {
  const float* nf   = (const float*)d_in[0];
  const float* ef1  = (const float*)d_in[1];
  const float* ef2  = (const float*)d_in[2];
  const float* W1   = (const float*)d_in[3];
  const float* W2   = (const float*)d_in[4];
  const int* from1  = (const int*)d_in[5];
  const int* seg1   = (const int*)d_in[6];
  const int* self1  = (const int*)d_in[7];
  const int* from2  = (const int*)d_in[8];
  const int* seg2   = (const int*)d_in[9];
  const int* self2  = (const int*)d_in[10];
  float* out = (float*)d_out;

  char* w = (char*)d_ws;
  size_t o = 0;
  auto take = [&](size_t nb) -> char* {
    char* p = w + o;
    o += (nb + 255) & ~(size_t)255;
    return p;
  };
  // zero region (cleared by setup1): cnt1, cnt2, mark, nn, zrow — ZERO_INTS ints
  int* cnt1 = (int*)take((size_t)M1 * 4);
  int* cnt2 = (int*)take((size_t)BSZ * 4);
  int* mark = (int*)take((size_t)M1 * 4);
  int* nn   = (int*)take(256);
  float* zrow = (float*)take((size_t)256 * 4);
  int* off1     = (int*)take((size_t)(M1 + 1) * 4);
  int* cur1     = (int*)take((size_t)M1 * 4);
  int* order1   = (int*)take((size_t)E1 * 4);
  int* fidx1    = (int*)take((size_t)E1 * 4);
  int* remap    = (int*)take((size_t)M1 * 4);
  int* needed   = (int*)take((size_t)8192 * 4);
  int* selfrow1 = (int*)take((size_t)8192 * 4);
  int* off2     = (int*)take((size_t)(BSZ + 1) * 4);
  int* cur2     = (int*)take((size_t)BSZ * 4);
  int* order2   = (int*)take((size_t)E2 * 4);
  int* fidx2    = (int*)take((size_t)E2 * 4);
  int2* wdesc   = (int2*)take((size_t)16384 * 8);
  unsigned short* Wb1   = (unsigned short*)take((size_t)WELEMS * 2);
  unsigned short* Wb2   = (unsigned short*)take((size_t)WELEMS * 2);
  unsigned short* agg1c = (unsigned short*)take((size_t)8192 * DAGG * 2);
  unsigned short* agg2  = (unsigned short*)take((size_t)8192 * DAGG * 2);
  unsigned short* h1c   = (unsigned short*)take((size_t)8192 * DOUT * 2);

  setup1_kernel<<<S1_ZB + S1_CB, 1024, 0, stream>>>((int*)d_ws, W1, W2, Wb1, Wb2);
  setup2_kernel<<<S2_MB + S2_CB, 1024, 0, stream>>>(self2, mark, seg1, cnt1, seg2, cnt2);
  setup3_kernel<<<S3_KB + 2, 1024, 0, stream>>>(mark, self1, remap, needed, selfrow1, nn,
                                                cnt1, off1, cur1, cnt2, off2, cur2);
  setup4_kernel<<<S4_EB + S4_DB, 1024, 0, stream>>>(seg1, mark, cur1, order1, fidx1, from1,
                                                    seg2, cur2, order2, fidx2, from2,
                                                    nn, needed, off1, off2, wdesc);
  agg_kernel<<<1024, 256, 0, stream>>>(wdesc, order1, fidx1, ef1, agg1c,
                                       order2, fidx2, ef2, agg2, nf, zrow);
  gemm_mfma_kernel<0><<<dim3(64, 4), 256, 0, stream>>>(nf, nullptr, selfrow1, nullptr,
                                                       agg1c, Wb1, nullptr, h1c, nn, 0);
  gemm_mfma_kernel<1><<<dim3(64, 4), 256, 0, stream>>>(nullptr, h1c, self2, remap,
                                                       agg2, Wb2, out, nullptr, nullptr, BSZ);
}

// Round 10
// 98.276 us; speedup vs baseline: 1.4590x; 1.4590x over previous
//
#include <hip/hip_runtime.h>
#include <hip/hip_bf16.h>

#define N_NODES 100000
#define DN      256
#define DE      128
#define DOUT    256
#define M1      32768
#define BSZ     8192
#define E1      327680
#define E2      81920
#define DIN     640
#define DAGG    384
#define WELEMS  (DOUT * DIN)

#define CDIV(a,b) (((a)+(b)-1)/(b))

// zero region: cnt1[M1] cnt2[BSZ] mark[M1] nn[64] zrow[256] — contiguous ints at ws base
#define ZERO_INTS (M1 + BSZ + M1 + 64 + 256)
#define S1_ZB 73            // CDIV(ZERO_INTS, 1024)
#define S1_CB 80            // 2*WELEMS / 4 / 1024
#define S2_MB 8             // BSZ / 1024 (mark blocks)
#define S2_EB 400           // (E1+E2) / 1024 (edge blocks)

typedef __attribute__((ext_vector_type(8))) short bf16x8;
typedef __attribute__((ext_vector_type(4))) float f32x4;
typedef __attribute__((ext_vector_type(2))) float f32x2;
typedef __attribute__((ext_vector_type(4))) unsigned short u16x4;
typedef __attribute__((ext_vector_type(2))) unsigned short u16x2;

__device__ __forceinline__ unsigned short f32_bf16(float f) {
  unsigned u = __float_as_uint(f);
  unsigned r = (u + 0x7FFF + ((u >> 16) & 1)) >> 16;
  return (unsigned short)r;
}

// ---- setup1: zero bookkeeping region + convert W1/W2 to bf16 --------------

__global__ __launch_bounds__(1024) void setup1_kernel(int* __restrict__ zbase,
                                                      const float* __restrict__ W1,
                                                      const float* __restrict__ W2,
                                                      unsigned short* __restrict__ Wb1,
                                                      unsigned short* __restrict__ Wb2) {
  int b = blockIdx.x, t = threadIdx.x;
  if (b < S1_ZB) {
    int i = b * 1024 + t;
    if (i < ZERO_INTS) zbase[i] = 0;
  } else {
    int i = ((b - S1_ZB) * 1024 + t) * 4;
    const float* s; unsigned short* d; int o;
    if (i < WELEMS) { s = W1; d = Wb1; o = i; }
    else { s = W2; d = Wb2; o = i - WELEMS; }
    f32x4 v = *reinterpret_cast<const f32x4*>(s + o);
    u16x4 r;
    r[0] = f32_bf16(v[0]); r[1] = f32_bf16(v[1]);
    r[2] = f32_bf16(v[2]); r[3] = f32_bf16(v[3]);
    *reinterpret_cast<u16x4*>(d + o) = r;
  }
}

// ---- setup2: mark live layer-1 segments + single-pass bucket CSR build ----
// bucket slot s holds up to 64 (from_idx, edge_id) pairs; cnt[s] = fill level.
// Segment sizes are Poisson(10); P(count > 64) < 1e-25 over all segments.

__global__ __launch_bounds__(1024) void setup2_kernel(const int* __restrict__ self2,
                                                      int* __restrict__ mark,
                                                      const int* __restrict__ seg1,
                                                      const int* __restrict__ from1,
                                                      int* __restrict__ cnt1,
                                                      int2* __restrict__ bkt1,
                                                      const int* __restrict__ seg2,
                                                      const int* __restrict__ from2,
                                                      int* __restrict__ cnt2,
                                                      int2* __restrict__ bkt2) {
  int b = blockIdx.x, t = threadIdx.x;
  if (b < S2_MB) {
    mark[self2[b * 1024 + t]] = 1;
  } else {
    int e = (b - S2_MB) * 1024 + t;
    if (e < E1) {
      int s = seg1[e];
      int p = atomicAdd(&cnt1[s], 1);
      if (p < 64) bkt1[s * 64 + p] = make_int2(from1[e], e);
    } else {
      int e2 = e - E1;
      int s = seg2[e2];
      int p = atomicAdd(&cnt2[s], 1);
      if (p < 64) bkt2[s * 64 + p] = make_int2(from2[e2], e2);
    }
  }
}

// ---- setup3: compact marked layer-1 segments ------------------------------

__global__ __launch_bounds__(1024) void setup3_kernel(const int* __restrict__ mark,
                                                      const int* __restrict__ self1,
                                                      int* __restrict__ remap,
                                                      int* __restrict__ needed,
                                                      int* __restrict__ selfrow1,
                                                      int* __restrict__ nn) {
  int m = blockIdx.x * 1024 + threadIdx.x;
  if (mark[m]) {
    int p = atomicAdd(nn, 1);
    remap[m] = p;
    needed[p] = m;
    selfrow1[p] = self1[m];
  }
}

// ---- aggregation: 4 segments per wave, bucket CSR (nc <= 64, no chunking) -
// Lane l owns nf cols [4l..4l+3] (f32x4) and ef cols [2l..2l+1] (f32x2).
// Head: per segment one int2 load/lane; gathers 8-wide with zero-padding.

__global__ __launch_bounds__(256) void agg_kernel(const int* __restrict__ needed,
                                                  const int* __restrict__ nn_dev,
                                                  const int* __restrict__ cnt1,
                                                  const int2* __restrict__ bkt1,
                                                  const float* __restrict__ ef1,
                                                  unsigned short* __restrict__ agg1,
                                                  const int* __restrict__ cnt2,
                                                  const int2* __restrict__ bkt2,
                                                  const float* __restrict__ ef2,
                                                  unsigned short* __restrict__ agg2,
                                                  const float* __restrict__ nf,
                                                  const float* __restrict__ zrow) {
  int wv = (blockIdx.x * 256 + threadIdx.x) >> 6;   // 0..4095
  int l = threadIdx.x & 63;
  int s0 = wv * 4;                                   // slot base (layer-aligned)
  bool lay1 = s0 < 8192;
  const int2* bkt = lay1 ? bkt1 : bkt2;
  const int* cnt  = lay1 ? cnt1 : cnt2;
  const float* ef = lay1 ? ef1 : ef2;
  unsigned short* aggout = lay1 ? agg1 : agg2;
  int rbase = lay1 ? s0 : s0 - 8192;

  int nnv = lay1 ? *nn_dev : 0;

  int base_[4], nc_[4];
#pragma unroll
  for (int s = 0; s < 4; ++s) {
    int m; bool valid;
    if (lay1) { valid = (s0 + s) < nnv; m = valid ? needed[s0 + s] : 0; }
    else      { valid = true; m = rbase + s; }
    nc_[s] = valid ? min(cnt[m], 64) : 0;
    base_[s] = m * 64;
  }

  int eidp[4], fidp[4];
#pragma unroll
  for (int s = 0; s < 4; ++s) {
    eidp[s] = 0; fidp[s] = 0;
    if (l < nc_[s]) {
      int2 d = bkt[base_[s] + l];
      fidp[s] = d.x; eidp[s] = d.y;
    }
  }

  const float* zra = zrow + l * 4;   // 16B of zeros per lane
  const float* zrb = zrow + l * 2;

  f32x4 accn[4];
  f32x2 accf[4];
#pragma unroll
  for (int s = 0; s < 4; ++s) {
    accn[s] = (f32x4)0.f;
    accf[s] = (f32x2)0.f;
    int nc = nc_[s];
    int eid = eidp[s], fid = fidp[s];
    for (int j = 0; j < nc; j += 8) {
      f32x4 a[8]; f32x2 b[8];
#pragma unroll
      for (int q = 0; q < 8; ++q) {
        int jj = j + q;
        int fq = __shfl(fid, jj & 63);
        int gq = __shfl(eid, jj & 63);
        bool ok = jj < nc;
        const float* pa = ok ? (nf + (size_t)fq * 256 + l * 4) : zra;
        const float* pb = ok ? (ef + (size_t)gq * 128 + l * 2) : zrb;
        a[q] = *reinterpret_cast<const f32x4*>(pa);
        b[q] = *reinterpret_cast<const f32x2*>(pb);
      }
      accn[s] += ((a[0] + a[1]) + (a[2] + a[3])) + ((a[4] + a[5]) + (a[6] + a[7]));
      accf[s] += ((b[0] + b[1]) + (b[2] + b[3])) + ((b[4] + b[5]) + (b[6] + b[7]));
    }
  }

#pragma unroll
  for (int s = 0; s < 4; ++s) {
    unsigned short* orow = aggout + (size_t)(rbase + s) * DAGG;
    u16x4 on;
    on[0] = f32_bf16(accn[s][0]); on[1] = f32_bf16(accn[s][1]);
    on[2] = f32_bf16(accn[s][2]); on[3] = f32_bf16(accn[s][3]);
    *reinterpret_cast<u16x4*>(orow + l * 4) = on;
    u16x2 oe;
    oe[0] = f32_bf16(accf[s][0]); oe[1] = f32_bf16(accf[s][1]);
    *reinterpret_cast<u16x2*>(orow + 256 + l * 2) = oe;
  }
}

// ---- MFMA GEMM (R8 known-best shape): BM=64, BN=64, BK=64, prefetch -------
// MODE 0 (layer1): table = nf (f32), row = i1[r];        out = bf16 h1
// MODE 1 (layer2): table = h1 (bf16), row = i2[i1[r]];   out = f32 final

template<int MODE>
__global__ __launch_bounds__(256, 4) void gemm_mfma_kernel(const float* __restrict__ tabf,
                                                           const unsigned short* __restrict__ tabb,
                                                           const int* __restrict__ i1,
                                                           const int* __restrict__ i2,
                                                           const unsigned short* __restrict__ agg,
                                                           const unsigned short* __restrict__ Wb,
                                                           float* __restrict__ outf,
                                                           unsigned short* __restrict__ outb,
                                                           const int* __restrict__ nn_dev,
                                                           int nrows_c) {
  const int nrows = nn_dev ? *nn_dev : nrows_c;
  const int row0 = blockIdx.x * 64;
  if (row0 >= nrows) return;
  const int col0 = blockIdx.y * 64;

  __shared__ unsigned short As[64][72];  // 144B row stride: 16B aligned, 2-way max
  __shared__ unsigned short Bs[64][72];

  const int t = threadIdx.x;
  const int lane = t & 63, wid = t >> 6;
  const int wm = wid >> 1, wn = wid & 1;

  // staging: thread t -> tile row (t>>2), k-cols (t&3)*16 .. +15
  const int srow = t >> 2;
  const int scol = (t & 3) * 16;
  const int grow = row0 + srow;
  int ga = -1;
  if (grow < nrows) { int x = i1[grow]; ga = (MODE == 1) ? i2[x] : x; }
  const unsigned short* wrow = Wb + (size_t)(col0 + srow) * DIN + scol;
  const float* tabrow_f = (MODE == 0 && ga >= 0) ? tabf + (size_t)ga * 256 : nullptr;
  const unsigned short* tabrow_b = (MODE == 1 && ga >= 0) ? tabb + (size_t)ga * 256 : nullptr;
  const unsigned short* aggrow = agg + (size_t)grow * DAGG;

  f32x4 acc[2][2];
#pragma unroll
  for (int m = 0; m < 2; ++m)
#pragma unroll
    for (int n = 0; n < 2; ++n) acc[m][n] = (f32x4)0.f;

  bf16x8 ra0, ra1, rb0, rb1;

  auto loadA = [&](int k0, bf16x8& r0, bf16x8& r1) {
    int k = k0 + scol;
    if (ga < 0) { r0 = (bf16x8)(short)0; r1 = (bf16x8)(short)0; return; }
    if (k < 256) {
      if (MODE == 0) {
        const float* s = tabrow_f + k;
        f32x4 x0 = *reinterpret_cast<const f32x4*>(s);
        f32x4 x1 = *reinterpret_cast<const f32x4*>(s + 4);
        f32x4 x2 = *reinterpret_cast<const f32x4*>(s + 8);
        f32x4 x3 = *reinterpret_cast<const f32x4*>(s + 12);
#pragma unroll
        for (int j = 0; j < 4; ++j) {
          r0[j] = (short)f32_bf16(x0[j]); r0[4 + j] = (short)f32_bf16(x1[j]);
          r1[j] = (short)f32_bf16(x2[j]); r1[4 + j] = (short)f32_bf16(x3[j]);
        }
      } else {
        r0 = *reinterpret_cast<const bf16x8*>(tabrow_b + k);
        r1 = *reinterpret_cast<const bf16x8*>(tabrow_b + k + 8);
      }
    } else {
      r0 = *reinterpret_cast<const bf16x8*>(aggrow + (k - 256));
      r1 = *reinterpret_cast<const bf16x8*>(aggrow + (k - 256) + 8);
    }
  };

  loadA(0, ra0, ra1);
  rb0 = *reinterpret_cast<const bf16x8*>(wrow);
  rb1 = *reinterpret_cast<const bf16x8*>(wrow + 8);

  for (int k0 = 0; k0 < DIN; k0 += 64) {
    *reinterpret_cast<bf16x8*>(&As[srow][scol]) = ra0;
    *reinterpret_cast<bf16x8*>(&As[srow][scol + 8]) = ra1;
    *reinterpret_cast<bf16x8*>(&Bs[srow][scol]) = rb0;
    *reinterpret_cast<bf16x8*>(&Bs[srow][scol + 8]) = rb1;
    __syncthreads();

    if (k0 + 64 < DIN) {  // issue next tile's loads before MFMA phase
      loadA(k0 + 64, ra0, ra1);
      rb0 = *reinterpret_cast<const bf16x8*>(wrow + k0 + 64);
      rb1 = *reinterpret_cast<const bf16x8*>(wrow + k0 + 64 + 8);
    }

#pragma unroll
    for (int ks = 0; ks < 2; ++ks) {
      bf16x8 af[2], bg[2];
#pragma unroll
      for (int m = 0; m < 2; ++m)
        af[m] = *reinterpret_cast<const bf16x8*>(
            &As[wm * 32 + m * 16 + (lane & 15)][ks * 32 + (lane >> 4) * 8]);
#pragma unroll
      for (int n = 0; n < 2; ++n)
        bg[n] = *reinterpret_cast<const bf16x8*>(
            &Bs[wn * 32 + n * 16 + (lane & 15)][ks * 32 + (lane >> 4) * 8]);
#pragma unroll
      for (int m = 0; m < 2; ++m)
#pragma unroll
        for (int n = 0; n < 2; ++n)
          acc[m][n] = __builtin_amdgcn_mfma_f32_16x16x32_bf16(af[m], bg[n], acc[m][n], 0, 0, 0);
    }
    __syncthreads();
  }

  const int rbase = row0 + wm * 32;
  const int cbase = col0 + wn * 32;
#pragma unroll
  for (int m = 0; m < 2; ++m)
#pragma unroll
    for (int n = 0; n < 2; ++n)
#pragma unroll
      for (int g = 0; g < 4; ++g) {
        int r = rbase + m * 16 + (lane >> 4) * 4 + g;
        if (r < nrows) {
          int c = cbase + n * 16 + (lane & 15);
          float x = fmaxf(acc[m][n][g], 0.f);
          if (MODE == 0) outb[(size_t)r * DOUT + c] = f32_bf16(x);
          else outf[(size_t)r * DOUT + c] = x;
        }
      }
}

// ---- launcher ------------------------------------------------------------

extern "C" void kernel_launch(void* const* d_in, const int* in_sizes, int n_in,
                              void* d_out, int out_size, void* d_ws, size_t ws_size,
                              hipStream_t stream) {
  const float* nf   = (const float*)d_in[0];
  const float* ef1  = (const float*)d_in[1];
  const float* ef2  = (const float*)d_in[2];
  const float* W1   = (const float*)d_in[3];
  const float* W2   = (const float*)d_in[4];
  const int* from1  = (const int*)d_in[5];
  const int* seg1   = (const int*)d_in[6];
  const int* self1  = (const int*)d_in[7];
  const int* from2  = (const int*)d_in[8];
  const int* seg2   = (const int*)d_in[9];
  const int* self2  = (const int*)d_in[10];
  float* out = (float*)d_out;

  char* w = (char*)d_ws;
  size_t o = 0;
  auto take = [&](size_t nb) -> char* {
    char* p = w + o;
    o += (nb + 255) & ~(size_t)255;
    return p;
  };
  // zero region (cleared by setup1): cnt1, cnt2, mark, nn, zrow — ZERO_INTS ints
  int* cnt1 = (int*)take((size_t)M1 * 4);
  int* cnt2 = (int*)take((size_t)BSZ * 4);
  int* mark = (int*)take((size_t)M1 * 4);
  int* nn   = (int*)take(256);
  float* zrow = (float*)take((size_t)256 * 4);
  int* remap    = (int*)take((size_t)M1 * 4);
  int* needed   = (int*)take((size_t)8192 * 4);
  int* selfrow1 = (int*)take((size_t)8192 * 4);
  int2* bkt1    = (int2*)take((size_t)M1 * 64 * 8);
  int2* bkt2    = (int2*)take((size_t)BSZ * 64 * 8);
  unsigned short* Wb1   = (unsigned short*)take((size_t)WELEMS * 2);
  unsigned short* Wb2   = (unsigned short*)take((size_t)WELEMS * 2);
  unsigned short* agg1c = (unsigned short*)take((size_t)8192 * DAGG * 2);
  unsigned short* agg2  = (unsigned short*)take((size_t)8192 * DAGG * 2);
  unsigned short* h1c   = (unsigned short*)take((size_t)8192 * DOUT * 2);

  setup1_kernel<<<S1_ZB + S1_CB, 1024, 0, stream>>>((int*)d_ws, W1, W2, Wb1, Wb2);
  setup2_kernel<<<S2_MB + S2_EB, 1024, 0, stream>>>(self2, mark, seg1, from1, cnt1, bkt1,
                                                    seg2, from2, cnt2, bkt2);
  setup3_kernel<<<M1 / 1024, 1024, 0, stream>>>(mark, self1, remap, needed, selfrow1, nn);
  agg_kernel<<<1024, 256, 0, stream>>>(needed, nn, cnt1, bkt1, ef1, agg1c,
                                       cnt2, bkt2, ef2, agg2, nf, zrow);
  gemm_mfma_kernel<0><<<dim3(128, 4), 256, 0, stream>>>(nf, nullptr, selfrow1, nullptr,
                                                        agg1c, Wb1, nullptr, h1c, nn, 0);
  gemm_mfma_kernel<1><<<dim3(128, 4), 256, 0, stream>>>(nullptr, h1c, self2, remap,
                                                        agg2, Wb2, out, nullptr, nullptr, BSZ);
}

// Round 11
// 94.548 us; speedup vs baseline: 1.5165x; 1.0394x over previous
//
#include <hip/hip_runtime.h>
#include <hip/hip_bf16.h>

#define N_NODES 100000
#define DN      256
#define DE      128
#define DOUT    256
#define M1      32768
#define BSZ     8192
#define E1      327680
#define E2      81920
#define DIN     640
#define DAGG    384
#define WELEMS  (DOUT * DIN)

#define CDIV(a,b) (((a)+(b)-1)/(b))

// zero region: cnt1[M1] cnt2[BSZ] claim[M1] nn[64] zrow[256] — contiguous ints at ws base
#define ZERO_INTS (M1 + BSZ + M1 + 64 + 256)
#define S1_ZB 73            // CDIV(ZERO_INTS, 1024)
#define S1_CB 80            // 2*WELEMS / 4 / 1024
#define S2_MB 8             // BSZ / 1024 (dedup blocks)
#define S2_EB 400           // (E1+E2) / 1024 (edge blocks)

typedef __attribute__((ext_vector_type(8))) short bf16x8;
typedef __attribute__((ext_vector_type(4))) float f32x4;
typedef __attribute__((ext_vector_type(2))) float f32x2;
typedef __attribute__((ext_vector_type(4))) unsigned short u16x4;
typedef __attribute__((ext_vector_type(2))) unsigned short u16x2;

__device__ __forceinline__ unsigned short f32_bf16(float f) {
  unsigned u = __float_as_uint(f);
  unsigned r = (u + 0x7FFF + ((u >> 16) & 1)) >> 16;
  return (unsigned short)r;
}

// ---- setup1: zero bookkeeping region + convert W1/W2 to bf16 --------------

__global__ __launch_bounds__(1024) void setup1_kernel(int* __restrict__ zbase,
                                                      const float* __restrict__ W1,
                                                      const float* __restrict__ W2,
                                                      unsigned short* __restrict__ Wb1,
                                                      unsigned short* __restrict__ Wb2) {
  int b = blockIdx.x, t = threadIdx.x;
  if (b < S1_ZB) {
    int i = b * 1024 + t;
    if (i < ZERO_INTS) zbase[i] = 0;
  } else {
    int i = ((b - S1_ZB) * 1024 + t) * 4;
    const float* s; unsigned short* d; int o;
    if (i < WELEMS) { s = W1; d = Wb1; o = i; }
    else { s = W2; d = Wb2; o = i - WELEMS; }
    f32x4 v = *reinterpret_cast<const f32x4*>(s + o);
    u16x4 r;
    r[0] = f32_bf16(v[0]); r[1] = f32_bf16(v[1]);
    r[2] = f32_bf16(v[2]); r[3] = f32_bf16(v[3]);
    *reinterpret_cast<u16x4*>(d + o) = r;
  }
}

// ---- setup2: CAS-dedup compaction of self2 + single-pass bucket CSR build -
// bucket slot s holds up to 64 (from_idx, edge_id) pairs; cnt[s] = fill level.
// Segment sizes are Poisson(10); P(count > 64) < 1e-25 over all segments.
// Dedup: winner of claim[m] allocates the compact slot p, writes remap[m]=p,
// needed[p]=m, selfrow1[p]=self1[m]. Slot ORDER varies with atomic timing but
// the mapping is permutation-consistent -> final output bit-identical.

__global__ __launch_bounds__(1024) void setup2_kernel(const int* __restrict__ self2,
                                                      int* __restrict__ claim,
                                                      const int* __restrict__ self1,
                                                      int* __restrict__ remap,
                                                      int* __restrict__ needed,
                                                      int* __restrict__ selfrow1,
                                                      int* __restrict__ nn,
                                                      const int* __restrict__ seg1,
                                                      const int* __restrict__ from1,
                                                      int* __restrict__ cnt1,
                                                      int2* __restrict__ bkt1,
                                                      const int* __restrict__ seg2,
                                                      const int* __restrict__ from2,
                                                      int* __restrict__ cnt2,
                                                      int2* __restrict__ bkt2) {
  int b = blockIdx.x, t = threadIdx.x;
  if (b < S2_MB) {
    int m = self2[b * 1024 + t];
    if (atomicCAS(&claim[m], 0, 1) == 0) {
      int p = atomicAdd(nn, 1);
      remap[m] = p;
      needed[p] = m;
      selfrow1[p] = self1[m];
    }
  } else {
    int e = (b - S2_MB) * 1024 + t;
    if (e < E1) {
      int s = seg1[e];
      int p = atomicAdd(&cnt1[s], 1);
      if (p < 64) bkt1[s * 64 + p] = make_int2(from1[e], e);
    } else {
      int e2 = e - E1;
      int s = seg2[e2];
      int p = atomicAdd(&cnt2[s], 1);
      if (p < 64) bkt2[s * 64 + p] = make_int2(from2[e2], e2);
    }
  }
}

// ---- aggregation: 2 segments per wave, bucket CSR (nc <= 64, no chunking) -
// Lane l owns nf cols [4l..4l+3] (f32x4) and ef cols [2l..2l+1] (f32x2).
// 8192 waves -> 8 waves/SIMD: max TLP on the gather stream.

__global__ __launch_bounds__(256) void agg_kernel(const int* __restrict__ needed,
                                                  const int* __restrict__ nn_dev,
                                                  const int* __restrict__ cnt1,
                                                  const int2* __restrict__ bkt1,
                                                  const float* __restrict__ ef1,
                                                  unsigned short* __restrict__ agg1,
                                                  const int* __restrict__ cnt2,
                                                  const int2* __restrict__ bkt2,
                                                  const float* __restrict__ ef2,
                                                  unsigned short* __restrict__ agg2,
                                                  const float* __restrict__ nf,
                                                  const float* __restrict__ zrow) {
  int wv = (blockIdx.x * 256 + threadIdx.x) >> 6;   // 0..8191
  int l = threadIdx.x & 63;
  int s0 = wv * 2;                                   // slot base (layer-aligned)
  bool lay1 = s0 < 8192;
  const int2* bkt = lay1 ? bkt1 : bkt2;
  const int* cnt  = lay1 ? cnt1 : cnt2;
  const float* ef = lay1 ? ef1 : ef2;
  unsigned short* aggout = lay1 ? agg1 : agg2;
  int rbase = lay1 ? s0 : s0 - 8192;

  int nnv = lay1 ? *nn_dev : 0;

  int base_[2], nc_[2];
#pragma unroll
  for (int s = 0; s < 2; ++s) {
    int m; bool valid;
    if (lay1) { valid = (s0 + s) < nnv; m = valid ? needed[s0 + s] : 0; }
    else      { valid = true; m = rbase + s; }
    nc_[s] = valid ? min(cnt[m], 64) : 0;
    base_[s] = m * 64;
  }

  int eidp[2], fidp[2];
#pragma unroll
  for (int s = 0; s < 2; ++s) {
    eidp[s] = 0; fidp[s] = 0;
    if (l < nc_[s]) {
      int2 d = bkt[base_[s] + l];
      fidp[s] = d.x; eidp[s] = d.y;
    }
  }

  const float* zra = zrow + l * 4;   // 16B of zeros per lane
  const float* zrb = zrow + l * 2;

  f32x4 accn[2];
  f32x2 accf[2];
#pragma unroll
  for (int s = 0; s < 2; ++s) {
    accn[s] = (f32x4)0.f;
    accf[s] = (f32x2)0.f;
    int nc = nc_[s];
    int eid = eidp[s], fid = fidp[s];
    for (int j = 0; j < nc; j += 8) {
      f32x4 a[8]; f32x2 b[8];
#pragma unroll
      for (int q = 0; q < 8; ++q) {
        int jj = j + q;
        int fq = __shfl(fid, jj & 63);
        int gq = __shfl(eid, jj & 63);
        bool ok = jj < nc;
        const float* pa = ok ? (nf + (size_t)fq * 256 + l * 4) : zra;
        const float* pb = ok ? (ef + (size_t)gq * 128 + l * 2) : zrb;
        a[q] = *reinterpret_cast<const f32x4*>(pa);
        b[q] = *reinterpret_cast<const f32x2*>(pb);
      }
      accn[s] += ((a[0] + a[1]) + (a[2] + a[3])) + ((a[4] + a[5]) + (a[6] + a[7]));
      accf[s] += ((b[0] + b[1]) + (b[2] + b[3])) + ((b[4] + b[5]) + (b[6] + b[7]));
    }
  }

#pragma unroll
  for (int s = 0; s < 2; ++s) {
    unsigned short* orow = aggout + (size_t)(rbase + s) * DAGG;
    u16x4 on;
    on[0] = f32_bf16(accn[s][0]); on[1] = f32_bf16(accn[s][1]);
    on[2] = f32_bf16(accn[s][2]); on[3] = f32_bf16(accn[s][3]);
    *reinterpret_cast<u16x4*>(orow + l * 4) = on;
    u16x2 oe;
    oe[0] = f32_bf16(accf[s][0]); oe[1] = f32_bf16(accf[s][1]);
    *reinterpret_cast<u16x2*>(orow + 256 + l * 2) = oe;
  }
}

// ---- MFMA GEMM (R8 known-best shape): BM=64, BN=64, BK=64, prefetch -------
// MODE 0 (layer1): table = nf (f32), row = i1[r];        out = bf16 h1
// MODE 1 (layer2): table = h1 (bf16), row = i2[i1[r]];   out = f32 final

template<int MODE>
__global__ __launch_bounds__(256, 4) void gemm_mfma_kernel(const float* __restrict__ tabf,
                                                           const unsigned short* __restrict__ tabb,
                                                           const int* __restrict__ i1,
                                                           const int* __restrict__ i2,
                                                           const unsigned short* __restrict__ agg,
                                                           const unsigned short* __restrict__ Wb,
                                                           float* __restrict__ outf,
                                                           unsigned short* __restrict__ outb,
                                                           const int* __restrict__ nn_dev,
                                                           int nrows_c) {
  const int nrows = nn_dev ? *nn_dev : nrows_c;
  const int row0 = blockIdx.x * 64;
  if (row0 >= nrows) return;
  const int col0 = blockIdx.y * 64;

  __shared__ unsigned short As[64][72];  // 144B row stride: 16B aligned, 2-way max
  __shared__ unsigned short Bs[64][72];

  const int t = threadIdx.x;
  const int lane = t & 63, wid = t >> 6;
  const int wm = wid >> 1, wn = wid & 1;

  // staging: thread t -> tile row (t>>2), k-cols (t&3)*16 .. +15
  const int srow = t >> 2;
  const int scol = (t & 3) * 16;
  const int grow = row0 + srow;
  int ga = -1;
  if (grow < nrows) { int x = i1[grow]; ga = (MODE == 1) ? i2[x] : x; }
  const unsigned short* wrow = Wb + (size_t)(col0 + srow) * DIN + scol;
  const float* tabrow_f = (MODE == 0 && ga >= 0) ? tabf + (size_t)ga * 256 : nullptr;
  const unsigned short* tabrow_b = (MODE == 1 && ga >= 0) ? tabb + (size_t)ga * 256 : nullptr;
  const unsigned short* aggrow = agg + (size_t)grow * DAGG;

  f32x4 acc[2][2];
#pragma unroll
  for (int m = 0; m < 2; ++m)
#pragma unroll
    for (int n = 0; n < 2; ++n) acc[m][n] = (f32x4)0.f;

  bf16x8 ra0, ra1, rb0, rb1;

  auto loadA = [&](int k0, bf16x8& r0, bf16x8& r1) {
    int k = k0 + scol;
    if (ga < 0) { r0 = (bf16x8)(short)0; r1 = (bf16x8)(short)0; return; }
    if (k < 256) {
      if (MODE == 0) {
        const float* s = tabrow_f + k;
        f32x4 x0 = *reinterpret_cast<const f32x4*>(s);
        f32x4 x1 = *reinterpret_cast<const f32x4*>(s + 4);
        f32x4 x2 = *reinterpret_cast<const f32x4*>(s + 8);
        f32x4 x3 = *reinterpret_cast<const f32x4*>(s + 12);
#pragma unroll
        for (int j = 0; j < 4; ++j) {
          r0[j] = (short)f32_bf16(x0[j]); r0[4 + j] = (short)f32_bf16(x1[j]);
          r1[j] = (short)f32_bf16(x2[j]); r1[4 + j] = (short)f32_bf16(x3[j]);
        }
      } else {
        r0 = *reinterpret_cast<const bf16x8*>(tabrow_b + k);
        r1 = *reinterpret_cast<const bf16x8*>(tabrow_b + k + 8);
      }
    } else {
      r0 = *reinterpret_cast<const bf16x8*>(aggrow + (k - 256));
      r1 = *reinterpret_cast<const bf16x8*>(aggrow + (k - 256) + 8);
    }
  };

  loadA(0, ra0, ra1);
  rb0 = *reinterpret_cast<const bf16x8*>(wrow);
  rb1 = *reinterpret_cast<const bf16x8*>(wrow + 8);

  for (int k0 = 0; k0 < DIN; k0 += 64) {
    *reinterpret_cast<bf16x8*>(&As[srow][scol]) = ra0;
    *reinterpret_cast<bf16x8*>(&As[srow][scol + 8]) = ra1;
    *reinterpret_cast<bf16x8*>(&Bs[srow][scol]) = rb0;
    *reinterpret_cast<bf16x8*>(&Bs[srow][scol + 8]) = rb1;
    __syncthreads();

    if (k0 + 64 < DIN) {  // issue next tile's loads before MFMA phase
      loadA(k0 + 64, ra0, ra1);
      rb0 = *reinterpret_cast<const bf16x8*>(wrow + k0 + 64);
      rb1 = *reinterpret_cast<const bf16x8*>(wrow + k0 + 64 + 8);
    }

#pragma unroll
    for (int ks = 0; ks < 2; ++ks) {
      bf16x8 af[2], bg[2];
#pragma unroll
      for (int m = 0; m < 2; ++m)
        af[m] = *reinterpret_cast<const bf16x8*>(
            &As[wm * 32 + m * 16 + (lane & 15)][ks * 32 + (lane >> 4) * 8]);
#pragma unroll
      for (int n = 0; n < 2; ++n)
        bg[n] = *reinterpret_cast<const bf16x8*>(
            &Bs[wn * 32 + n * 16 + (lane & 15)][ks * 32 + (lane >> 4) * 8]);
#pragma unroll
      for (int m = 0; m < 2; ++m)
#pragma unroll
        for (int n = 0; n < 2; ++n)
          acc[m][n] = __builtin_amdgcn_mfma_f32_16x16x32_bf16(af[m], bg[n], acc[m][n], 0, 0, 0);
    }
    __syncthreads();
  }

  const int rbase = row0 + wm * 32;
  const int cbase = col0 + wn * 32;
#pragma unroll
  for (int m = 0; m < 2; ++m)
#pragma unroll
    for (int n = 0; n < 2; ++n)
#pragma unroll
      for (int g = 0; g < 4; ++g) {
        int r = rbase + m * 16 + (lane >> 4) * 4 + g;
        if (r < nrows) {
          int c = cbase + n * 16 + (lane & 15);
          float x = fmaxf(acc[m][n][g], 0.f);
          if (MODE == 0) outb[(size_t)r * DOUT + c] = f32_bf16(x);
          else outf[(size_t)r * DOUT + c] = x;
        }
      }
}

// ---- launcher ------------------------------------------------------------

extern "C" void kernel_launch(void* const* d_in, const int* in_sizes, int n_in,
                              void* d_out, int out_size, void* d_ws, size_t ws_size,
                              hipStream_t stream) {
  const float* nf   = (const float*)d_in[0];
  const float* ef1  = (const float*)d_in[1];
  const float* ef2  = (const float*)d_in[2];
  const float* W1   = (const float*)d_in[3];
  const float* W2   = (const float*)d_in[4];
  const int* from1  = (const int*)d_in[5];
  const int* seg1   = (const int*)d_in[6];
  const int* self1  = (const int*)d_in[7];
  const int* from2  = (const int*)d_in[8];
  const int* seg2   = (const int*)d_in[9];
  const int* self2  = (const int*)d_in[10];
  float* out = (float*)d_out;

  char* w = (char*)d_ws;
  size_t o = 0;
  auto take = [&](size_t nb) -> char* {
    char* p = w + o;
    o += (nb + 255) & ~(size_t)255;
    return p;
  };
  // zero region (cleared by setup1): cnt1, cnt2, claim, nn, zrow — ZERO_INTS ints
  int* cnt1 = (int*)take((size_t)M1 * 4);
  int* cnt2 = (int*)take((size_t)BSZ * 4);
  int* claim = (int*)take((size_t)M1 * 4);
  int* nn   = (int*)take(256);
  float* zrow = (float*)take((size_t)256 * 4);
  int* remap    = (int*)take((size_t)M1 * 4);
  int* needed   = (int*)take((size_t)8192 * 4);
  int* selfrow1 = (int*)take((size_t)8192 * 4);
  int2* bkt1    = (int2*)take((size_t)M1 * 64 * 8);
  int2* bkt2    = (int2*)take((size_t)BSZ * 64 * 8);
  unsigned short* Wb1   = (unsigned short*)take((size_t)WELEMS * 2);
  unsigned short* Wb2   = (unsigned short*)take((size_t)WELEMS * 2);
  unsigned short* agg1c = (unsigned short*)take((size_t)8192 * DAGG * 2);
  unsigned short* agg2  = (unsigned short*)take((size_t)8192 * DAGG * 2);
  unsigned short* h1c   = (unsigned short*)take((size_t)8192 * DOUT * 2);

  setup1_kernel<<<S1_ZB + S1_CB, 1024, 0, stream>>>((int*)d_ws, W1, W2, Wb1, Wb2);
  setup2_kernel<<<S2_MB + S2_EB, 1024, 0, stream>>>(self2, claim, self1, remap, needed,
                                                    selfrow1, nn,
                                                    seg1, from1, cnt1, bkt1,
                                                    seg2, from2, cnt2, bkt2);
  agg_kernel<<<2048, 256, 0, stream>>>(needed, nn, cnt1, bkt1, ef1, agg1c,
                                       cnt2, bkt2, ef2, agg2, nf, zrow);
  gemm_mfma_kernel<0><<<dim3(128, 4), 256, 0, stream>>>(nf, nullptr, selfrow1, nullptr,
                                                        agg1c, Wb1, nullptr, h1c, nn, 0);
  gemm_mfma_kernel<1><<<dim3(128, 4), 256, 0, stream>>>(nullptr, h1c, self2, remap,
                                                        agg2, Wb2, out, nullptr, nullptr, BSZ);
}

// Round 12
// 90.118 us; speedup vs baseline: 1.5910x; 1.0492x over previous
//
#include <hip/hip_runtime.h>
#include <hip/hip_bf16.h>

#define N_NODES 100000
#define DN      256
#define DE      128
#define DOUT    256
#define M1      32768
#define BSZ     8192
#define E1      327680
#define E2      81920
#define DIN     640
#define DAGG    384
#define WELEMS  (DOUT * DIN)

#define CDIV(a,b) (((a)+(b)-1)/(b))

// zero region: cnt1[M1] cnt2[BSZ] claim[M1] nn[64] zrow[256] — contiguous ints at ws base
#define ZERO_INTS (M1 + BSZ + M1 + 64 + 256)
#define S1_ZB 73            // CDIV(ZERO_INTS, 1024)
#define S1_CB 80            // 2*WELEMS / 4 / 1024
#define S2_MB 8             // BSZ / 1024 (dedup blocks)
#define S2_EB 400           // (E1+E2) / 1024 (edge blocks)
#define GEMM1_BLOCKS 512    // 128 row-tiles x 4 col-tiles

typedef __attribute__((ext_vector_type(8))) short bf16x8;
typedef __attribute__((ext_vector_type(4))) float f32x4;
typedef __attribute__((ext_vector_type(2))) float f32x2;
typedef __attribute__((ext_vector_type(4))) unsigned short u16x4;
typedef __attribute__((ext_vector_type(2))) unsigned short u16x2;

__device__ __forceinline__ unsigned short f32_bf16(float f) {
  unsigned u = __float_as_uint(f);
  unsigned r = (u + 0x7FFF + ((u >> 16) & 1)) >> 16;
  return (unsigned short)r;
}

// ---- setup1: zero bookkeeping region + convert W1/W2 to bf16 --------------

__global__ __launch_bounds__(1024) void setup1_kernel(int* __restrict__ zbase,
                                                      const float* __restrict__ W1,
                                                      const float* __restrict__ W2,
                                                      unsigned short* __restrict__ Wb1,
                                                      unsigned short* __restrict__ Wb2) {
  int b = blockIdx.x, t = threadIdx.x;
  if (b < S1_ZB) {
    int i = b * 1024 + t;
    if (i < ZERO_INTS) zbase[i] = 0;
  } else {
    int i = ((b - S1_ZB) * 1024 + t) * 4;
    const float* s; unsigned short* d; int o;
    if (i < WELEMS) { s = W1; d = Wb1; o = i; }
    else { s = W2; d = Wb2; o = i - WELEMS; }
    f32x4 v = *reinterpret_cast<const f32x4*>(s + o);
    u16x4 r;
    r[0] = f32_bf16(v[0]); r[1] = f32_bf16(v[1]);
    r[2] = f32_bf16(v[2]); r[3] = f32_bf16(v[3]);
    *reinterpret_cast<u16x4*>(d + o) = r;
  }
}

// ---- setup2: CAS-dedup compaction of self2 + single-pass bucket CSR build -

__global__ __launch_bounds__(1024) void setup2_kernel(const int* __restrict__ self2,
                                                      int* __restrict__ claim,
                                                      const int* __restrict__ self1,
                                                      int* __restrict__ remap,
                                                      int* __restrict__ needed,
                                                      int* __restrict__ selfrow1,
                                                      int* __restrict__ nn,
                                                      const int* __restrict__ seg1,
                                                      const int* __restrict__ from1,
                                                      int* __restrict__ cnt1,
                                                      int2* __restrict__ bkt1,
                                                      const int* __restrict__ seg2,
                                                      const int* __restrict__ from2,
                                                      int* __restrict__ cnt2,
                                                      int2* __restrict__ bkt2) {
  int b = blockIdx.x, t = threadIdx.x;
  if (b < S2_MB) {
    int m = self2[b * 1024 + t];
    if (atomicCAS(&claim[m], 0, 1) == 0) {
      int p = atomicAdd(nn, 1);
      remap[m] = p;
      needed[p] = m;
      selfrow1[p] = self1[m];
    }
  } else {
    int e = (b - S2_MB) * 1024 + t;
    if (e < E1) {
      int s = seg1[e];
      int p = atomicAdd(&cnt1[s], 1);
      if (p < 64) bkt1[s * 64 + p] = make_int2(from1[e], e);
    } else {
      int e2 = e - E1;
      int s = seg2[e2];
      int p = atomicAdd(&cnt2[s], 1);
      if (p < 64) bkt2[s * 64 + p] = make_int2(from2[e2], e2);
    }
  }
}

// ---- shared device body: aggregate 2 segments for one wave ----------------
// Lane l owns nf cols [4l..4l+3] (f32x4) and ef cols [2l..2l+1] (f32x2).

__device__ __forceinline__ void agg_two_segments(int m0, bool v0, int m1, bool v1,
                                                 int r0, const int* __restrict__ cnt,
                                                 const int2* __restrict__ bkt,
                                                 const float* __restrict__ ef,
                                                 unsigned short* __restrict__ aggout,
                                                 const float* __restrict__ nf,
                                                 const float* __restrict__ zrow,
                                                 int l) {
  int mm[2] = {m0, m1};
  bool vv[2] = {v0, v1};
  int base_[2], nc_[2];
#pragma unroll
  for (int s = 0; s < 2; ++s) {
    nc_[s] = vv[s] ? min(cnt[mm[s]], 64) : 0;
    base_[s] = mm[s] * 64;
  }
  int eidp[2], fidp[2];
#pragma unroll
  for (int s = 0; s < 2; ++s) {
    eidp[s] = 0; fidp[s] = 0;
    if (l < nc_[s]) {
      int2 d = bkt[base_[s] + l];
      fidp[s] = d.x; eidp[s] = d.y;
    }
  }
  const float* zra = zrow + l * 4;
  const float* zrb = zrow + l * 2;

  f32x4 accn[2];
  f32x2 accf[2];
#pragma unroll
  for (int s = 0; s < 2; ++s) {
    accn[s] = (f32x4)0.f;
    accf[s] = (f32x2)0.f;
    int nc = nc_[s];
    int eid = eidp[s], fid = fidp[s];
    for (int j = 0; j < nc; j += 8) {
      f32x4 a[8]; f32x2 b[8];
#pragma unroll
      for (int q = 0; q < 8; ++q) {
        int jj = j + q;
        int fq = __shfl(fid, jj & 63);
        int gq = __shfl(eid, jj & 63);
        bool ok = jj < nc;
        const float* pa = ok ? (nf + (size_t)fq * 256 + l * 4) : zra;
        const float* pb = ok ? (ef + (size_t)gq * 128 + l * 2) : zrb;
        a[q] = *reinterpret_cast<const f32x4*>(pa);
        b[q] = *reinterpret_cast<const f32x2*>(pb);
      }
      accn[s] += ((a[0] + a[1]) + (a[2] + a[3])) + ((a[4] + a[5]) + (a[6] + a[7]));
      accf[s] += ((b[0] + b[1]) + (b[2] + b[3])) + ((b[4] + b[5]) + (b[6] + b[7]));
    }
  }

#pragma unroll
  for (int s = 0; s < 2; ++s) {
    unsigned short* orow = aggout + (size_t)(r0 + s) * DAGG;
    u16x4 on;
    on[0] = f32_bf16(accn[s][0]); on[1] = f32_bf16(accn[s][1]);
    on[2] = f32_bf16(accn[s][2]); on[3] = f32_bf16(accn[s][3]);
    *reinterpret_cast<u16x4*>(orow + l * 4) = on;
    u16x2 oe;
    oe[0] = f32_bf16(accf[s][0]); oe[1] = f32_bf16(accf[s][1]);
    *reinterpret_cast<u16x2*>(orow + 256 + l * 2) = oe;
  }
}

// ---- agg1: layer-1 live segments only (critical path) ---------------------

__global__ __launch_bounds__(256) void agg1_kernel(const int* __restrict__ needed,
                                                   const int* __restrict__ nn_dev,
                                                   const int* __restrict__ cnt1,
                                                   const int2* __restrict__ bkt1,
                                                   const float* __restrict__ ef1,
                                                   unsigned short* __restrict__ agg1,
                                                   const float* __restrict__ nf,
                                                   const float* __restrict__ zrow) {
  int wv = (blockIdx.x * 256 + threadIdx.x) >> 6;   // 0..4095
  int l = threadIdx.x & 63;
  int s0 = wv * 2;
  int nnv = *nn_dev;
  bool v0 = s0 < nnv, v1 = (s0 + 1) < nnv;
  if (!v0) return;
  int m0 = needed[s0];
  int m1 = v1 ? needed[s0 + 1] : 0;
  agg_two_segments(m0, v0, m1, v1, s0, cnt1, bkt1, ef1, agg1, nf, zrow, l);
}

// ---- GEMM device body (R8 shape: BM=64, BN=64, BK=64, prefetch) -----------
// MODE 0 (layer1): table = nf (f32), row = i1[r];        out = bf16 h1
// MODE 1 (layer2): table = h1 (bf16), row = i2[i1[r]];   out = f32 final

template<int MODE>
__device__ __forceinline__ void gemm_body(int bx, int by,
                                          const float* __restrict__ tabf,
                                          const unsigned short* __restrict__ tabb,
                                          const int* __restrict__ i1,
                                          const int* __restrict__ i2,
                                          const unsigned short* __restrict__ agg,
                                          const unsigned short* __restrict__ Wb,
                                          float* __restrict__ outf,
                                          unsigned short* __restrict__ outb,
                                          int nrows) {
  const int row0 = bx * 64;
  if (row0 >= nrows) return;
  const int col0 = by * 64;

  __shared__ unsigned short As[64][72];
  __shared__ unsigned short Bs[64][72];

  const int t = threadIdx.x;
  const int lane = t & 63, wid = t >> 6;
  const int wm = wid >> 1, wn = wid & 1;

  const int srow = t >> 2;
  const int scol = (t & 3) * 16;
  const int grow = row0 + srow;
  int ga = -1;
  if (grow < nrows) { int x = i1[grow]; ga = (MODE == 1) ? i2[x] : x; }
  const unsigned short* wrow = Wb + (size_t)(col0 + srow) * DIN + scol;
  const float* tabrow_f = (MODE == 0 && ga >= 0) ? tabf + (size_t)ga * 256 : nullptr;
  const unsigned short* tabrow_b = (MODE == 1 && ga >= 0) ? tabb + (size_t)ga * 256 : nullptr;
  const unsigned short* aggrow = agg + (size_t)grow * DAGG;

  f32x4 acc[2][2];
#pragma unroll
  for (int m = 0; m < 2; ++m)
#pragma unroll
    for (int n = 0; n < 2; ++n) acc[m][n] = (f32x4)0.f;

  bf16x8 ra0, ra1, rb0, rb1;

  auto loadA = [&](int k0, bf16x8& r0, bf16x8& r1) {
    int k = k0 + scol;
    if (ga < 0) { r0 = (bf16x8)(short)0; r1 = (bf16x8)(short)0; return; }
    if (k < 256) {
      if (MODE == 0) {
        const float* s = tabrow_f + k;
        f32x4 x0 = *reinterpret_cast<const f32x4*>(s);
        f32x4 x1 = *reinterpret_cast<const f32x4*>(s + 4);
        f32x4 x2 = *reinterpret_cast<const f32x4*>(s + 8);
        f32x4 x3 = *reinterpret_cast<const f32x4*>(s + 12);
#pragma unroll
        for (int j = 0; j < 4; ++j) {
          r0[j] = (short)f32_bf16(x0[j]); r0[4 + j] = (short)f32_bf16(x1[j]);
          r1[j] = (short)f32_bf16(x2[j]); r1[4 + j] = (short)f32_bf16(x3[j]);
        }
      } else {
        r0 = *reinterpret_cast<const bf16x8*>(tabrow_b + k);
        r1 = *reinterpret_cast<const bf16x8*>(tabrow_b + k + 8);
      }
    } else {
      r0 = *reinterpret_cast<const bf16x8*>(aggrow + (k - 256));
      r1 = *reinterpret_cast<const bf16x8*>(aggrow + (k - 256) + 8);
    }
  };

  loadA(0, ra0, ra1);
  rb0 = *reinterpret_cast<const bf16x8*>(wrow);
  rb1 = *reinterpret_cast<const bf16x8*>(wrow + 8);

  for (int k0 = 0; k0 < DIN; k0 += 64) {
    *reinterpret_cast<bf16x8*>(&As[srow][scol]) = ra0;
    *reinterpret_cast<bf16x8*>(&As[srow][scol + 8]) = ra1;
    *reinterpret_cast<bf16x8*>(&Bs[srow][scol]) = rb0;
    *reinterpret_cast<bf16x8*>(&Bs[srow][scol + 8]) = rb1;
    __syncthreads();

    if (k0 + 64 < DIN) {
      loadA(k0 + 64, ra0, ra1);
      rb0 = *reinterpret_cast<const bf16x8*>(wrow + k0 + 64);
      rb1 = *reinterpret_cast<const bf16x8*>(wrow + k0 + 64 + 8);
    }

#pragma unroll
    for (int ks = 0; ks < 2; ++ks) {
      bf16x8 af[2], bg[2];
#pragma unroll
      for (int m = 0; m < 2; ++m)
        af[m] = *reinterpret_cast<const bf16x8*>(
            &As[wm * 32 + m * 16 + (lane & 15)][ks * 32 + (lane >> 4) * 8]);
#pragma unroll
      for (int n = 0; n < 2; ++n)
        bg[n] = *reinterpret_cast<const bf16x8*>(
            &Bs[wn * 32 + n * 16 + (lane & 15)][ks * 32 + (lane >> 4) * 8]);
#pragma unroll
      for (int m = 0; m < 2; ++m)
#pragma unroll
        for (int n = 0; n < 2; ++n)
          acc[m][n] = __builtin_amdgcn_mfma_f32_16x16x32_bf16(af[m], bg[n], acc[m][n], 0, 0, 0);
    }
    __syncthreads();
  }

  const int rbase = row0 + wm * 32;
  const int cbase = col0 + wn * 32;
#pragma unroll
  for (int m = 0; m < 2; ++m)
#pragma unroll
    for (int n = 0; n < 2; ++n)
#pragma unroll
      for (int g = 0; g < 4; ++g) {
        int r = rbase + m * 16 + (lane >> 4) * 4 + g;
        if (r < nrows) {
          int c = cbase + n * 16 + (lane & 15);
          float x = fmaxf(acc[m][n][g], 0.f);
          if (MODE == 0) outb[(size_t)r * DOUT + c] = f32_bf16(x);
          else outf[(size_t)r * DOUT + c] = x;
        }
      }
}

// ---- fused: gemm1 (blocks 0..511) || agg2 (blocks 512..1535) --------------
// The two halves are data-independent; they co-schedule across the machine.

__global__ __launch_bounds__(256, 4) void gemm1_agg2_kernel(const float* __restrict__ nf,
                                                            const int* __restrict__ selfrow1,
                                                            const unsigned short* __restrict__ agg1,
                                                            const unsigned short* __restrict__ Wb1,
                                                            unsigned short* __restrict__ h1c,
                                                            const int* __restrict__ nn_dev,
                                                            const int* __restrict__ cnt2,
                                                            const int2* __restrict__ bkt2,
                                                            const float* __restrict__ ef2,
                                                            unsigned short* __restrict__ agg2,
                                                            const float* __restrict__ zrow) {
  int b = blockIdx.x;
  if (b < GEMM1_BLOCKS) {
    gemm_body<0>(b >> 2, b & 3, nf, nullptr, selfrow1, nullptr, agg1, Wb1,
                 nullptr, h1c, *nn_dev);
  } else {
    int wv = ((b - GEMM1_BLOCKS) * 256 + threadIdx.x) >> 6;  // 0..4095
    int l = threadIdx.x & 63;
    int s0 = wv * 2;                                          // 0..8190
    agg_two_segments(s0, true, s0 + 1, true, s0, cnt2, bkt2, ef2, agg2,
                     nf, zrow, l);
  }
}

// ---- gemm2 ----------------------------------------------------------------

__global__ __launch_bounds__(256, 4) void gemm2_kernel(const unsigned short* __restrict__ h1c,
                                                       const int* __restrict__ self2,
                                                       const int* __restrict__ remap,
                                                       const unsigned short* __restrict__ agg2,
                                                       const unsigned short* __restrict__ Wb2,
                                                       float* __restrict__ out) {
  gemm_body<1>(blockIdx.x, blockIdx.y, nullptr, h1c, self2, remap, agg2, Wb2,
               out, nullptr, BSZ);
}

// ---- launcher ------------------------------------------------------------

extern "C" void kernel_launch(void* const* d_in, const int* in_sizes, int n_in,
                              void* d_out, int out_size, void* d_ws, size_t ws_size,
                              hipStream_t stream) {
  const float* nf   = (const float*)d_in[0];
  const float* ef1  = (const float*)d_in[1];
  const float* ef2  = (const float*)d_in[2];
  const float* W1   = (const float*)d_in[3];
  const float* W2   = (const float*)d_in[4];
  const int* from1  = (const int*)d_in[5];
  const int* seg1   = (const int*)d_in[6];
  const int* self1  = (const int*)d_in[7];
  const int* from2  = (const int*)d_in[8];
  const int* seg2   = (const int*)d_in[9];
  const int* self2  = (const int*)d_in[10];
  float* out = (float*)d_out;

  char* w = (char*)d_ws;
  size_t o = 0;
  auto take = [&](size_t nb) -> char* {
    char* p = w + o;
    o += (nb + 255) & ~(size_t)255;
    return p;
  };
  // zero region (cleared by setup1): cnt1, cnt2, claim, nn, zrow — ZERO_INTS ints
  int* cnt1 = (int*)take((size_t)M1 * 4);
  int* cnt2 = (int*)take((size_t)BSZ * 4);
  int* claim = (int*)take((size_t)M1 * 4);
  int* nn   = (int*)take(256);
  float* zrow = (float*)take((size_t)256 * 4);
  int* remap    = (int*)take((size_t)M1 * 4);
  int* needed   = (int*)take((size_t)8192 * 4);
  int* selfrow1 = (int*)take((size_t)8192 * 4);
  int2* bkt1    = (int2*)take((size_t)M1 * 64 * 8);
  int2* bkt2    = (int2*)take((size_t)BSZ * 64 * 8);
  unsigned short* Wb1   = (unsigned short*)take((size_t)WELEMS * 2);
  unsigned short* Wb2   = (unsigned short*)take((size_t)WELEMS * 2);
  unsigned short* agg1c = (unsigned short*)take((size_t)8192 * DAGG * 2);
  unsigned short* agg2  = (unsigned short*)take((size_t)8192 * DAGG * 2);
  unsigned short* h1c   = (unsigned short*)take((size_t)8192 * DOUT * 2);

  setup1_kernel<<<S1_ZB + S1_CB, 1024, 0, stream>>>((int*)d_ws, W1, W2, Wb1, Wb2);
  setup2_kernel<<<S2_MB + S2_EB, 1024, 0, stream>>>(self2, claim, self1, remap, needed,
                                                    selfrow1, nn,
                                                    seg1, from1, cnt1, bkt1,
                                                    seg2, from2, cnt2, bkt2);
  agg1_kernel<<<1024, 256, 0, stream>>>(needed, nn, cnt1, bkt1, ef1, agg1c, nf, zrow);
  gemm1_agg2_kernel<<<GEMM1_BLOCKS + 1024, 256, 0, stream>>>(nf, selfrow1, agg1c, Wb1,
                                                             h1c, nn,
                                                             cnt2, bkt2, ef2, agg2, zrow);
  gemm2_kernel<<<dim3(128, 4), 256, 0, stream>>>(h1c, self2, remap, agg2, Wb2, out);
}